// Round 5
// baseline (1386.909 us; speedup 1.0000x reference)
//
#include <hip/hip_runtime.h>

// CATSCluster: fused 3-stream MLP (768->256->128) + combine on MI355X.
// Round N+5: fuse p1+p2 GEMM1 K-loops (they share W1!).
//  Round-4 negative: smaller blocks doubled per-row barrier+W-traffic cost
//  and re-spilled -> reverted to the round-3 skeleton (512 thr, 64 rows,
//  2 blocks/CU).
//  Round-3 stall: ~60% idle; dominant chain = 8 serial W-pair global loads
//  per wave per interval (lane-stride 1536B, ~16 lines/instr) with only
//  6 MFMAs between pairs -- and the chain is paid TWICE (p1, p2 same W1).
//  Fix: one fused K=32 interval stages A-tiles for BOTH p-streams and loads
//  each W1 (Bh,Bl) pair once -> 24 MFMAs per pair (4x fewer B-instrs),
//  W1 L2 traffic per block halved. q-stream keeps round-3 K=64 loop.
//  LDS time-multiplexed union (fused-A 41KB -> H 33.8KB + q-A 36.9KB),
//  total 72.7KB = round-3 footprint -> 2 blocks/CU.
//  A-frags re-read per n from LDS (throughput-cheap) to keep regs ~105<=128.
// Numerics bitwise-identical to round 3: per-acc MFMA term order (AhBh,
// AhBl, AlBh) and ascending-K order preserved; fp32 combine unchanged.

typedef short short8 __attribute__((ext_vector_type(8)));   // 8 x bf16 (4 VGPRs)
typedef float f32x4 __attribute__((ext_vector_type(4)));    // MFMA accumulator

// d_ws layout (in unsigned short elements)
#define W1H_OFF 0u
#define W1L_OFF 196608u
#define W3H_OFF 393216u
#define W3L_OFF 589824u
#define W2H_OFF 786432u
#define W2L_OFF 819200u
#define W4H_OFF 851968u
#define W4L_OFF 884736u
// lo plane = hi plane + 196608 (W1/W3) or + 32768 (W2/W4)

__device__ __forceinline__ unsigned short bf16_rne(float f) {
  unsigned int u = __float_as_uint(f);
  u += 0x7FFFu + ((u >> 16) & 1u);      // round-to-nearest-even
  return (unsigned short)(u >> 16);
}

__device__ __forceinline__ void split_bf16(float f, unsigned short& h, unsigned short& l) {
  h = bf16_rne(f);
  float fh = __uint_as_float(((unsigned int)h) << 16);
  l = bf16_rne(f - fh);                 // residual; |x - hi - lo| ~ 2^-18 |x|
}

__device__ __forceinline__ void pack_split4(const float4 v, uint2& ph, uint2& pl) {
  unsigned short h0,h1,h2,h3,l0,l1,l2,l3;
  split_bf16(v.x,h0,l0); split_bf16(v.y,h1,l1);
  split_bf16(v.z,h2,l2); split_bf16(v.w,h3,l3);
  ph.x = (unsigned)h0 | ((unsigned)h1 << 16); ph.y = (unsigned)h2 | ((unsigned)h3 << 16);
  pl.x = (unsigned)l0 | ((unsigned)l1 << 16); pl.y = (unsigned)l2 | ((unsigned)l3 << 16);
}

__global__ __launch_bounds__(256) void prep_weights(
    const float* __restrict__ W1, const float* __restrict__ W2,
    const float* __restrict__ W3, const float* __restrict__ W4,
    unsigned short* __restrict__ ws)
{
  int i = blockIdx.x * 256 + threadIdx.x;
  if (i < 196608) {
    unsigned short h, l;
    split_bf16(W1[i], h, l); ws[W1H_OFF + i] = h; ws[W1L_OFF + i] = l;
    split_bf16(W3[i], h, l); ws[W3H_OFF + i] = h; ws[W3L_OFF + i] = l;
    if (i < 32768) {
      split_bf16(W2[i], h, l); ws[W2H_OFF + i] = h; ws[W2L_OFF + i] = l;
      split_bf16(W4[i], h, l); ws[W4H_OFF + i] = h; ws[W4L_OFF + i] = l;
    }
  }
}

#define SA32 40            // A-row stride (shorts), K=32 tiles (fused phase)
#define P32  (64 * SA32)   // 2560 shorts per plane
#define SA64 72            // A-row stride (shorts), K=64 tiles (q phase)
#define P64  (64 * SA64)   // 4608 shorts per plane
#define SH   264           // H-row stride (shorts)
#define HSZ  (64 * SH)     // 16896 shorts

// LDS union timeline (shorts):
//   fused phase : A2[2 dbuf][2 stream][2 plane][P32]  = 20480   [0..20480)
//   later       : H [HSZ=16896)                        [0..16896)
//                 Aq[2 dbuf][2 plane][P64]  = 18432    [16896..35328)
#define SMEM_SHORTS 35328

__global__ __launch_bounds__(512, 4) void catsc_main(
    const float* __restrict__ X, const unsigned short* __restrict__ ws,
    const float* __restrict__ W5, float* __restrict__ out)
{
  __shared__ short smem[SMEM_SHORTS];     // 70,656 B
  __shared__ float lsPart[8][64];         //  2,048 B  -> total 72,704 B

  const int tid  = threadIdx.x;
  const int wave = tid >> 6;      // 0..7
  const int lane = tid & 63;
  const int l15  = lane & 15;
  const int q    = lane >> 4;     // quad index 0..3
  const int blk  = blockIdx.x;    // 0..1023, 64 rows each

  // X_data is (16, 4097, 2304); skip row 0 of each n.
  const float* Xb = X + (size_t)((blk >> 6) * 4097 + 1 + ((blk & 63) << 6)) * 2304;

  // staging coords
  const int srow = tid >> 3;              // 0..63
  const int c32  = (tid & 7) << 2;        // 4-float seg within 32-col interval
  const int c64  = (tid & 7) << 3;        // 8-float seg within 64-col interval
  const float* Xs = Xb + (size_t)srow * 2304;
  const int si32 = srow * SA32 + c32;
  const int si64 = srow * SA64 + c64;

  // fragment coords
  const int arow32 = l15 * SA32 + q * 8;
  const int arow64 = l15 * SA64 + q * 8;
  const size_t bwl = (size_t)(wave * 32 + l15) * 768 + q * 8;
  const size_t cwl = (size_t)(wave * 16 + l15) * 256 + q * 8;
  const int hrow = l15 * SH + q * 8;

  const unsigned short* W1b = ws + W1H_OFF + bwl;
  const unsigned short* W3b = ws + W3H_OFF + bwl;
  const unsigned short* W2b = ws + W2H_OFF + cwl;
  const unsigned short* W4b = ws + W4H_OFF + cwl;

  auto storeH = [&](f32x4 (&a)[4][2]) {
#pragma unroll
    for (int m = 0; m < 4; ++m)
#pragma unroll
      for (int n = 0; n < 2; ++n) {
        const int col = wave * 32 + n * 16 + l15;
#pragma unroll
        for (int i = 0; i < 4; ++i)
          smem[(m * 16 + q * 4 + i) * SH + col] = bf16_rne(fmaxf(a[m][n][i], 0.f));
      }
  };

  auto gemm2 = [&](const unsigned short* Cb, f32x4 (&o)[4]) {
#pragma unroll
    for (int m = 0; m < 4; ++m) o[m] = f32x4{0.f, 0.f, 0.f, 0.f};
    for (int c2 = 0; c2 < 8; ++c2) {
      const unsigned short* cp = Cb + c2 * 32;
      short8 Ch = *(const short8*)cp;
      short8 Cl = *(const short8*)(cp + 32768);
      short8 Ha[4];
#pragma unroll
      for (int m = 0; m < 4; ++m)
        Ha[m] = *(const short8*)&smem[m * 16 * SH + hrow + c2 * 32];
#pragma unroll
      for (int m = 0; m < 4; ++m)
        o[m] = __builtin_amdgcn_mfma_f32_16x16x32_bf16(Ha[m], Ch, o[m], 0, 0, 0);
#pragma unroll
      for (int m = 0; m < 4; ++m)
        o[m] = __builtin_amdgcn_mfma_f32_16x16x32_bf16(Ha[m], Cl, o[m], 0, 0, 0);
    }
  };

  // ================= fused GEMM1 for p1 (cols 768..) + p2 (cols 1536..) ====
  f32x4 acc[2][4][2];
#pragma unroll
  for (int t = 0; t < 2; ++t)
#pragma unroll
    for (int m = 0; m < 4; ++m)
#pragma unroll
      for (int n = 0; n < 2; ++n)
        acc[t][m][n] = f32x4{0.f, 0.f, 0.f, 0.f};

  {
    // interval-0 X for both streams, then stage
    float4 vF0 = *(const float4*)(Xs + 768 + c32);
    float4 vF1 = *(const float4*)(Xs + 1536 + c32);
    uint2 ph, pl;
    pack_split4(vF0, ph, pl);
    *(uint2*)&smem[si32]       = ph; *(uint2*)&smem[P32 + si32]     = pl;
    pack_split4(vF1, ph, pl);
    *(uint2*)&smem[2*P32+si32] = ph; *(uint2*)&smem[3*P32 + si32]   = pl;
  }
  __syncthreads();

#pragma unroll 1
  for (int p = 0; p < 24; ++p) {
    const int b = p & 1;
    float4 v0, v1;
    if (p + 1 < 24) {              // depth-1 prefetch, both streams
      v0 = *(const float4*)(Xs + 768  + (p + 1) * 32 + c32);
      v1 = *(const float4*)(Xs + 1536 + (p + 1) * 32 + c32);
    }
    const short* Ab = smem + b * (4 * P32);

#pragma unroll
    for (int n = 0; n < 2; ++n) {
      // one W1 pair feeds both streams (24 MFMAs)
      const unsigned short* bp = W1b + n * 12288 + p * 32;
      short8 Bh = *(const short8*)bp;
      short8 Bl = *(const short8*)(bp + 196608);
#pragma unroll
      for (int t = 0; t < 2; ++t) {
        const short* a0 = Ab + t * (2 * P32) + arow32;
#pragma unroll
        for (int mh = 0; mh < 2; ++mh) {
          short8 Ah[2], Al[2];
#pragma unroll
          for (int mm = 0; mm < 2; ++mm) {
            const int a = (mh * 2 + mm) * 16 * SA32;
            Ah[mm] = *(const short8*)(a0 + a);
            Al[mm] = *(const short8*)(a0 + P32 + a);
          }
          acc[t][mh*2+0][n] = __builtin_amdgcn_mfma_f32_16x16x32_bf16(Ah[0], Bh, acc[t][mh*2+0][n], 0, 0, 0);
          acc[t][mh*2+1][n] = __builtin_amdgcn_mfma_f32_16x16x32_bf16(Ah[1], Bh, acc[t][mh*2+1][n], 0, 0, 0);
          acc[t][mh*2+0][n] = __builtin_amdgcn_mfma_f32_16x16x32_bf16(Ah[0], Bl, acc[t][mh*2+0][n], 0, 0, 0);
          acc[t][mh*2+1][n] = __builtin_amdgcn_mfma_f32_16x16x32_bf16(Ah[1], Bl, acc[t][mh*2+1][n], 0, 0, 0);
          acc[t][mh*2+0][n] = __builtin_amdgcn_mfma_f32_16x16x32_bf16(Al[0], Bh, acc[t][mh*2+0][n], 0, 0, 0);
          acc[t][mh*2+1][n] = __builtin_amdgcn_mfma_f32_16x16x32_bf16(Al[1], Bh, acc[t][mh*2+1][n], 0, 0, 0);
        }
      }
    }

    if (p + 1 < 24) {              // stage interval p+1, both streams
      short* d = smem + (b ^ 1) * (4 * P32);
      uint2 ph, pl;
      pack_split4(v0, ph, pl);
      *(uint2*)&d[si32]           = ph; *(uint2*)&d[P32 + si32]     = pl;
      pack_split4(v1, ph, pl);
      *(uint2*)&d[2*P32 + si32]   = ph; *(uint2*)&d[3*P32 + si32]   = pl;
    }
    __syncthreads();
  }

  // ======== transition: H(p1) -> GEMM2 p1 ; H(p2) -> GEMM2 p2 ============
  // T14: q-stream interval-0 X issued now, consumed below
  float4 vQ0 = *(const float4*)(Xs + c64);
  float4 vQ1 = *(const float4*)(Xs + c64 + 4);

  storeH(acc[0]);                       // lsH <- relu(p1)
  __syncthreads();                      // B1

  f32x4 acc2[4];
  f32x4 zp[4];
  gemm2(W2b, acc2);                     // p1 -> acc2
  {                                     // stage q interval 0 (disjoint from lsH)
    short* Aq = smem + HSZ;
    uint2 ph, pl;
    pack_split4(vQ0, ph, pl);
    *(uint2*)&Aq[si64]     = ph; *(uint2*)&Aq[P64 + si64]     = pl;
    pack_split4(vQ1, ph, pl);
    *(uint2*)&Aq[si64 + 4] = ph; *(uint2*)&Aq[P64 + si64 + 4] = pl;
  }
#pragma unroll
  for (int m = 0; m < 4; ++m)
#pragma unroll
    for (int i = 0; i < 4; ++i)
      zp[m][i] = fmaxf(acc2[m][i], 0.f);
  __syncthreads();                      // B2: all H(p1) reads done; Aq0 visible

  storeH(acc[1]);                       // lsH <- relu(p2)
  __syncthreads();                      // B3

  gemm2(W2b, acc2);                     // p2 -> acc2
#pragma unroll
  for (int m = 0; m < 4; ++m)
#pragma unroll
    for (int i = 0; i < 4; ++i)
      zp[m][i] = fabsf(zp[m][i] - fmaxf(acc2[m][i], 0.f));

  // ================= q-stream GEMM1 (round-3 structure, K=64 x 12) ========
  f32x4 aq[4][2];
#pragma unroll
  for (int m = 0; m < 4; ++m)
#pragma unroll
    for (int n = 0; n < 2; ++n)
      aq[m][n] = f32x4{0.f, 0.f, 0.f, 0.f};

#pragma unroll 1
  for (int p = 0; p < 12; ++p) {
    const int b = p & 1;
    float4 w0, w1;
    if (p + 1 < 12) {
      w0 = *(const float4*)(Xs + (p + 1) * 64 + c64);
      w1 = *(const float4*)(Xs + (p + 1) * 64 + c64 + 4);
    }
    const short* A0 = smem + HSZ + b * (2 * P64);

#pragma unroll
    for (int sub = 0; sub < 2; ++sub) {
#pragma unroll
      for (int n = 0; n < 2; ++n) {
        const unsigned short* bp = W3b + n * 12288 + p * 64 + sub * 32;
        short8 Bh = *(const short8*)bp;
        short8 Bl = *(const short8*)(bp + 196608);
#pragma unroll
        for (int mh = 0; mh < 2; ++mh) {
          short8 Ah[2], Al[2];
#pragma unroll
          for (int mm = 0; mm < 2; ++mm) {
            const int a = (mh * 2 + mm) * 16 * SA64 + sub * 32 + arow64;
            Ah[mm] = *(const short8*)(A0 + a);
            Al[mm] = *(const short8*)(A0 + P64 + a);
          }
          aq[mh*2+0][n] = __builtin_amdgcn_mfma_f32_16x16x32_bf16(Ah[0], Bh, aq[mh*2+0][n], 0, 0, 0);
          aq[mh*2+1][n] = __builtin_amdgcn_mfma_f32_16x16x32_bf16(Ah[1], Bh, aq[mh*2+1][n], 0, 0, 0);
          aq[mh*2+0][n] = __builtin_amdgcn_mfma_f32_16x16x32_bf16(Ah[0], Bl, aq[mh*2+0][n], 0, 0, 0);
          aq[mh*2+1][n] = __builtin_amdgcn_mfma_f32_16x16x32_bf16(Ah[1], Bl, aq[mh*2+1][n], 0, 0, 0);
          aq[mh*2+0][n] = __builtin_amdgcn_mfma_f32_16x16x32_bf16(Al[0], Bh, aq[mh*2+0][n], 0, 0, 0);
          aq[mh*2+1][n] = __builtin_amdgcn_mfma_f32_16x16x32_bf16(Al[1], Bh, aq[mh*2+1][n], 0, 0, 0);
        }
      }
    }

    if (p + 1 < 12) {
      short* d = smem + HSZ + (b ^ 1) * (2 * P64);
      uint2 ph, pl;
      pack_split4(w0, ph, pl);
      *(uint2*)&d[si64]     = ph; *(uint2*)&d[P64 + si64]     = pl;
      pack_split4(w1, ph, pl);
      *(uint2*)&d[si64 + 4] = ph; *(uint2*)&d[P64 + si64 + 4] = pl;
    }
    __syncthreads();
  }

  // ================= H(q) -> GEMM2 q -> combine ===========================
  storeH(aq);
  __syncthreads();

  gemm2(W4b, acc2);                     // q -> acc2
  {
    const float w5c = W5[wave * 16 + l15];
#pragma unroll
    for (int m = 0; m < 4; ++m)
#pragma unroll
      for (int i = 0; i < 4; ++i) {
        float v = fmaxf(acc2[m][i], 0.f) * zp[m][i] * w5c;
        v += __shfl_xor(v, 1);
        v += __shfl_xor(v, 2);
        v += __shfl_xor(v, 4);
        v += __shfl_xor(v, 8);
        if (l15 == 0) lsPart[wave][m * 16 + q * 4 + i] = v;
      }
  }
  __syncthreads();
  if (tid < 64) {
    float sum = lsPart[0][tid] + lsPart[1][tid] + lsPart[2][tid] + lsPart[3][tid]
              + lsPart[4][tid] + lsPart[5][tid] + lsPart[6][tid] + lsPart[7][tid];
    out[(size_t)blk * 64 + tid] = tanhf(fmaxf(sum, 0.f));
  }
}

extern "C" void kernel_launch(void* const* d_in, const int* in_sizes, int n_in,
                              void* d_out, int out_size, void* d_ws, size_t ws_size,
                              hipStream_t stream) {
  const float* X  = (const float*)d_in[0];
  const float* W1 = (const float*)d_in[1];
  const float* W2 = (const float*)d_in[2];
  const float* W3 = (const float*)d_in[3];
  const float* W4 = (const float*)d_in[4];
  const float* W5 = (const float*)d_in[5];
  float* out = (float*)d_out;
  unsigned short* ws = (unsigned short*)d_ws;  // needs 1.75 MB

  prep_weights<<<dim3(768), dim3(256), 0, stream>>>(W1, W2, W3, W4, ws);
  catsc_main<<<dim3(1024), dim3(512), 0, stream>>>(X, ws, W5, out);
}